// Round 2
// baseline (405.697 us; speedup 1.0000x reference)
//
#include <hip/hip_runtime.h>
#include <hip/hip_bf16.h>
#include <stdint.h>

// Problem constants (fixed by the reference file)
#define NB 8     // batch
#define NS 2048  // sequence
#define ND 1536  // model dim (K)
#define NT 2048  // padded tracks (N)
#define NH 8     // heads
#define NK (ND / 32)  // 48 K-iterations

// NUM_TRACKS = [128,256,512,1024,2048,64,32,1024] -> ceil(nt/128)*128
__constant__ int c_nlim[NH] = {128, 256, 512, 1024, 2048, 128, 128, 1024};

typedef short bf16x8 __attribute__((ext_vector_type(8)));  // 8 bf16 (4 VGPRs)
typedef unsigned short u16x8 __attribute__((ext_vector_type(8)));
typedef float f32x4 __attribute__((ext_vector_type(4)));

__device__ __forceinline__ unsigned short f2bf(float f) {
    union { float f; unsigned u; } a; a.f = f;
    unsigned r = a.u + 0x7fffu + ((a.u >> 16) & 1u);  // RNE
    return (unsigned short)(r >> 16);
}

// ---------------- Prepass 1: x fp32 -> bf16 ----------------
__global__ void cvt_x_kernel(const float* __restrict__ x,
                             unsigned short* __restrict__ xb) {
    const size_t i = (size_t)blockIdx.x * 256 + threadIdx.x;  // float4 index
    float4 v = ((const float4*)x)[i];
    ushort4 o;
    o.x = f2bf(v.x); o.y = f2bf(v.y); o.z = f2bf(v.z); o.w = f2bf(v.w);
    ((ushort4*)xb)[i] = o;
}

// ---------------- Prepass 2: W[h][d][t] fp32 -> Wt[h][t][d] bf16 ----------
// 64x64 tile, 32 B/thread stores. Only used heads, only t < c_nlim[h].
__global__ void cvt_w_kernel(const float* __restrict__ W,
                             const int* __restrict__ hidx,
                             unsigned short* __restrict__ Wt) {
    const int h = blockIdx.z;
    bool used = false;
    for (int i = 0; i < NB; ++i) used |= (hidx[i] == h);
    if (!used) return;
    const int t0 = blockIdx.x * 64;
    if (t0 >= c_nlim[h]) return;
    const int d0 = blockIdx.y * 64;

    __shared__ float tile[64][69];  // [d][t], pad 69 -> 2-way max on read
    const int tid = threadIdx.x;
#pragma unroll
    for (int i = 0; i < 4; ++i) {
        const int idx = tid + i * 256;         // 1024 float4 chunks
        const int d = idx >> 4, c = (idx & 15) * 4;
        float4 v = *(const float4*)&W[((size_t)h * ND + d0 + d) * NT + t0 + c];
        tile[d][c] = v.x; tile[d][c + 1] = v.y;
        tile[d][c + 2] = v.z; tile[d][c + 3] = v.w;
    }
    __syncthreads();
    const int t = tid >> 2, dc = (tid & 3) * 16;  // 16 bf16 = 32 B per thread
    u16x8 o0, o1;
#pragma unroll
    for (int j = 0; j < 8; ++j) o0[j] = f2bf(tile[dc + j][t]);
#pragma unroll
    for (int j = 0; j < 8; ++j) o1[j] = f2bf(tile[dc + 8 + j][t]);
    unsigned short* p = Wt + ((size_t)h * NT + t0 + t) * ND + d0 + dc;
    *(u16x8*)p = o0;
    *(u16x8*)(p + 8) = o1;
}

// ---------------- GEMM: out[b] = x[b] @ W[h(b)] + bias[h(b)] ----------------
// m97 structure + explicit LDS double-buffer: GLDS for tile k+1 issued before
// computing tile k; single barrier per iter. At ~2.5 compute blocks/CU there
// is no implicit wave-level overlap, so the prefetch matters here.
#define GLDS(g, l)                                                      \
    __builtin_amdgcn_global_load_lds(                                   \
        (const __attribute__((address_space(1))) void*)(g),             \
        (__attribute__((address_space(3))) void*)(l), 16, 0, 0)

__global__ __launch_bounds__(256) void gemm_kernel(
    const unsigned short* __restrict__ xb,   // bf16 [NB][NS][ND]
    const unsigned short* __restrict__ wt,   // bf16 [NH][NT][ND]
    const float* __restrict__ bias,          // fp32 [NH][NT]
    const int* __restrict__ hidx,            // [NB]
    float* __restrict__ out)                 // fp32 [NB][NS][NT]
{
    const int batch = blockIdx.z;
    const int m0 = blockIdx.y * 128;
    const int n0 = blockIdx.x * 128;
    const int h = hidx[batch];
    const int tid = threadIdx.x;
    float* outb = out + (size_t)batch * NS * NT;

    if (n0 >= c_nlim[h]) {
        // Pure zero tile: W and bias are exactly zero here -> logits == 0.
        const int row = tid >> 1;
        const int c0 = (tid & 1) * 64;
        float4 z = make_float4(0.f, 0.f, 0.f, 0.f);
        float4* p = (float4*)(outb + (size_t)(m0 + row) * NT + (n0 + c0));
#pragma unroll
        for (int j = 0; j < 16; ++j) p[j] = z;
        return;
    }

    __shared__ unsigned short As[2][128 * 32];  // [m][k] row-major
    __shared__ unsigned short Bs[2][128 * 32];  // [n][k] row-major (B^T)

    const int lane = tid & 63;
    const int wave = tid >> 6;
    const int wm = (wave >> 1) * 64;
    const int wn = (wave & 1) * 64;
    const int fr = lane & 15;        // m (A) / n (B) / col (C)
    const int fq = (lane >> 4) * 8;  // k-group

    // Staging: 512 16B-chunks per tile; thread handles chunks tid and tid+256.
    const int r0 = tid >> 2, kc0 = (tid & 3) * 8;
    const int i1 = tid + 256;
    const int r1 = i1 >> 2, kc1 = (i1 & 3) * 8;

    const unsigned short* ga0 = xb + ((size_t)batch * NS + m0 + r0) * ND + kc0;
    const unsigned short* ga1 = xb + ((size_t)batch * NS + m0 + r1) * ND + kc1;
    const unsigned short* gb0 = wt + ((size_t)h * NT + n0 + r0) * ND + kc0;
    const unsigned short* gb1 = wt + ((size_t)h * NT + n0 + r1) * ND + kc1;

    f32x4 acc[4][4] = {};

    // Preload tile 0 into buffer 0.
    GLDS(ga0, &As[0][tid * 8]); GLDS(ga1, &As[0][i1 * 8]);
    GLDS(gb0, &Bs[0][tid * 8]); GLDS(gb1, &Bs[0][i1 * 8]);

    for (int it = 0; it < NK; ++it) {
        const int cur = it & 1;
        __syncthreads();  // drains vmcnt(0): buffer `cur` is ready
        if (it + 1 < NK) {
            const int nxt = cur ^ 1;
            ga0 += 32; ga1 += 32; gb0 += 32; gb1 += 32;
            GLDS(ga0, &As[nxt][tid * 8]); GLDS(ga1, &As[nxt][i1 * 8]);
            GLDS(gb0, &Bs[nxt][tid * 8]); GLDS(gb1, &Bs[nxt][i1 * 8]);
        }
        bf16x8 af[4], bfr[4];
#pragma unroll
        for (int mi = 0; mi < 4; ++mi)
            af[mi] = *(const bf16x8*)(&As[cur][(wm + mi * 16 + fr) * 32 + fq]);
#pragma unroll
        for (int ni = 0; ni < 4; ++ni)
            bfr[ni] = *(const bf16x8*)(&Bs[cur][(wn + ni * 16 + fr) * 32 + fq]);
#pragma unroll
        for (int mi = 0; mi < 4; ++mi)
#pragma unroll
            for (int ni = 0; ni < 4; ++ni)
                acc[mi][ni] = __builtin_amdgcn_mfma_f32_16x16x32_bf16(
                    af[mi], bfr[ni], acc[mi][ni], 0, 0, 0);
    }

    // Epilogue: C/D layout col=lane&15, row=(lane>>4)*4+reg
    float bv[4];
#pragma unroll
    for (int ni = 0; ni < 4; ++ni)
        bv[ni] = bias[(size_t)h * NT + n0 + wn + ni * 16 + fr];

    const int rbase = m0 + wm + (lane >> 4) * 4;
#pragma unroll
    for (int mi = 0; mi < 4; ++mi) {
#pragma unroll
        for (int r = 0; r < 4; ++r) {
            float* op = outb + (size_t)(rbase + mi * 16 + r) * NT + n0 + wn + fr;
#pragma unroll
            for (int ni = 0; ni < 4; ++ni)
                op[ni * 16] = acc[mi][ni][r] + bv[ni];
        }
    }
}

extern "C" void kernel_launch(void* const* d_in, const int* in_sizes, int n_in,
                              void* d_out, int out_size, void* d_ws, size_t ws_size,
                              hipStream_t stream) {
    const float* x    = (const float*)d_in[0];  // [NB][NS][ND] fp32
    const int*   hidx = (const int*)d_in[1];    // [NB] int32
    const float* W    = (const float*)d_in[2];  // [NH][ND][NT] fp32
    const float* bias = (const float*)d_in[3];  // [NH][NT] fp32
    float* out = (float*)d_out;

    unsigned short* xb = (unsigned short*)d_ws;            // 48 MiB bf16 x
    unsigned short* wt = xb + (size_t)NB * NS * ND;        // 48 MiB bf16 W^T

    // x convert: 25165824 floats = 6291456 float4s / 256 = 24576 blocks
    cvt_x_kernel<<<dim3(24576), dim3(256), 0, stream>>>(x, xb);
    // W transpose+convert: (T/64, D/64, H)
    cvt_w_kernel<<<dim3(NT / 64, ND / 64, NH), dim3(256), 0, stream>>>(W, hidx, wt);
    // GEMM: (N/128, M/128, B)
    gemm_kernel<<<dim3(NT / 128, NS / 128, NB), dim3(256), 0, stream>>>(
        xb, wt, bias, hidx, out);
}

// Round 3
// 352.943 us; speedup vs baseline: 1.1495x; 1.1495x over previous
//
#include <hip/hip_runtime.h>
#include <hip/hip_bf16.h>
#include <stdint.h>

// Problem constants (fixed by the reference file)
#define NB 8     // batch
#define NS 2048  // sequence
#define ND 1536  // model dim (K)
#define NT 2048  // padded tracks (N)
#define NH 8     // heads
#define NK (ND / 32)  // 48 K-iterations

// NUM_TRACKS = [128,256,512,1024,2048,64,32,1024] -> ceil(nt/128)*128
__constant__ int c_nlim[NH] = {128, 256, 512, 1024, 2048, 128, 128, 1024};

typedef short bf16x8 __attribute__((ext_vector_type(8)));  // 8 bf16 (4 VGPRs)
typedef unsigned short u16x8 __attribute__((ext_vector_type(8)));
typedef float f32x4 __attribute__((ext_vector_type(4)));

__device__ __forceinline__ unsigned short f2bf(float f) {
    union { float f; unsigned u; } a; a.f = f;
    unsigned r = a.u + 0x7fffu + ((a.u >> 16) & 1u);  // RNE
    return (unsigned short)(r >> 16);
}

// ---------------- Fused prepass: x fp32->bf16  +  W transpose+convert -------
// Blocks [0, 24576): x convert (one float4 per thread).
// Blocks [24576, 24576+6144): W[h][d][t] -> Wt[h][t][d] bf16, 64x64 tiles.
#define XBLK 24576
__global__ void cvt_kernel(const float* __restrict__ x,
                           const float* __restrict__ W,
                           const int* __restrict__ hidx,
                           unsigned short* __restrict__ xb,
                           unsigned short* __restrict__ Wt) {
    const int bid = blockIdx.x;
    const int tid = threadIdx.x;
    if (bid < XBLK) {
        const size_t i = (size_t)bid * 256 + tid;  // float4 index
        float4 v = ((const float4*)x)[i];
        ushort4 o;
        o.x = f2bf(v.x); o.y = f2bf(v.y); o.z = f2bf(v.z); o.w = f2bf(v.w);
        ((ushort4*)xb)[i] = o;
        return;
    }
    // W transpose: wid -> (t-tile 32, d-tile 24, h 8)
    const int wid = bid - XBLK;
    const int h = wid / (32 * 24);
    const int rem = wid % (32 * 24);
    const int t0 = (rem % 32) * 64;
    const int d0 = (rem / 32) * 64;
    bool used = false;
    for (int i = 0; i < NB; ++i) used |= (hidx[i] == h);
    if (!used || t0 >= c_nlim[h]) return;

    __shared__ float tile[64][69];  // [d][t], padded
#pragma unroll
    for (int i = 0; i < 4; ++i) {
        const int idx = tid + i * 256;  // 1024 float4 chunks
        const int d = idx >> 4, c = (idx & 15) * 4;
        float4 v = *(const float4*)&W[((size_t)h * ND + d0 + d) * NT + t0 + c];
        tile[d][c] = v.x; tile[d][c + 1] = v.y;
        tile[d][c + 2] = v.z; tile[d][c + 3] = v.w;
    }
    __syncthreads();
    const int t = tid >> 2, dc = (tid & 3) * 16;  // 16 bf16 = 32 B per thread
    u16x8 o0, o1;
#pragma unroll
    for (int j = 0; j < 8; ++j) o0[j] = f2bf(tile[dc + j][t]);
#pragma unroll
    for (int j = 0; j < 8; ++j) o1[j] = f2bf(tile[dc + 8 + j][t]);
    unsigned short* p = Wt + ((size_t)h * NT + t0 + t) * ND + d0 + dc;
    *(u16x8*)p = o0;
    *(u16x8*)(p + 8) = o1;
}

// ---------------- GEMM: out[b] = x[b] @ W[h(b)] + bias[h(b)] ----------------
// Round-1 single-buffer m97 structure + LOAD-BALANCED block swizzle.
// Naive (x,y,z) grid gives CU c the same n-column for all 8 batches ->
// compute blocks pile onto low-n CUs (measured Occupancy 13% = 1 block/CU).
// Swizzle: id=(q<<8)|r; m=r>>4, n=((r&15)+2q)&15, batch=((r&15)+q)&7 is a
// bijection and gives every CU all 8 batches and 8 distinct n-columns.
#define GLDS(g, l)                                                      \
    __builtin_amdgcn_global_load_lds(                                   \
        (const __attribute__((address_space(1))) void*)(g),             \
        (__attribute__((address_space(3))) void*)(l), 16, 0, 0)

__global__ __launch_bounds__(256) void gemm_kernel(
    const unsigned short* __restrict__ xb,   // bf16 [NB][NS][ND]
    const unsigned short* __restrict__ wt,   // bf16 [NH][NT][ND]
    const float* __restrict__ bias,          // fp32 [NH][NT]
    const int* __restrict__ hidx,            // [NB]
    float* __restrict__ out)                 // fp32 [NB][NS][NT]
{
    const int id = blockIdx.x;
    const int q = id >> 8, r = id & 255;
    const int nr = r & 15;
    const int m0 = (r >> 4) * 128;
    const int n0 = (((nr + 2 * q) & 15)) * 128;
    const int batch = (nr + q) & 7;
    const int h = hidx[batch];
    const int tid = threadIdx.x;
    float* outb = out + (size_t)batch * NS * NT;

    if (n0 >= c_nlim[h]) {
        // Pure zero tile: W and bias are exactly zero here -> logits == 0.
        const int row = tid >> 1;
        const int c0 = (tid & 1) * 64;
        float4 z = make_float4(0.f, 0.f, 0.f, 0.f);
        float4* p = (float4*)(outb + (size_t)(m0 + row) * NT + (n0 + c0));
#pragma unroll
        for (int j = 0; j < 16; ++j) p[j] = z;
        return;
    }

    __shared__ unsigned short As[128 * 32];  // [m][k] row-major
    __shared__ unsigned short Bs[128 * 32];  // [n][k] row-major (B^T)

    const int lane = tid & 63;
    const int wave = tid >> 6;
    const int wm = (wave >> 1) * 64;
    const int wn = (wave & 1) * 64;
    const int fr = lane & 15;        // m (A) / n (B) / col (C)
    const int fq = (lane >> 4) * 8;  // k-group

    // Staging: 512 16B-chunks per tile; thread handles chunks tid and tid+256.
    const int r0 = tid >> 2, kc0 = (tid & 3) * 8;
    const int i1 = tid + 256;
    const int r1 = i1 >> 2, kc1 = (i1 & 3) * 8;

    const unsigned short* ga0 = xb + ((size_t)batch * NS + m0 + r0) * ND + kc0;
    const unsigned short* ga1 = xb + ((size_t)batch * NS + m0 + r1) * ND + kc1;
    const unsigned short* gb0 = wt + ((size_t)h * NT + n0 + r0) * ND + kc0;
    const unsigned short* gb1 = wt + ((size_t)h * NT + n0 + r1) * ND + kc1;
    unsigned short* la0 = As + tid * 8;
    unsigned short* la1 = As + i1 * 8;
    unsigned short* lb0 = Bs + tid * 8;
    unsigned short* lb1 = Bs + i1 * 8;

    f32x4 acc[4][4] = {};

    for (int k0 = 0; k0 < ND; k0 += 32) {
        GLDS(ga0, la0); GLDS(ga1, la1); GLDS(gb0, lb0); GLDS(gb1, lb1);
        __syncthreads();
        bf16x8 af[4], bfr[4];
#pragma unroll
        for (int mi = 0; mi < 4; ++mi)
            af[mi] = *(const bf16x8*)(As + (wm + mi * 16 + fr) * 32 + fq);
#pragma unroll
        for (int ni = 0; ni < 4; ++ni)
            bfr[ni] = *(const bf16x8*)(Bs + (wn + ni * 16 + fr) * 32 + fq);
#pragma unroll
        for (int mi = 0; mi < 4; ++mi)
#pragma unroll
            for (int ni = 0; ni < 4; ++ni)
                acc[mi][ni] = __builtin_amdgcn_mfma_f32_16x16x32_bf16(
                    af[mi], bfr[ni], acc[mi][ni], 0, 0, 0);
        __syncthreads();
        ga0 += 32; ga1 += 32; gb0 += 32; gb1 += 32;
    }

    // Epilogue: C/D layout col=lane&15, row=(lane>>4)*4+reg
    float bv[4];
#pragma unroll
    for (int ni = 0; ni < 4; ++ni)
        bv[ni] = bias[(size_t)h * NT + n0 + wn + ni * 16 + fr];

    const int rbase = m0 + wm + (lane >> 4) * 4;
#pragma unroll
    for (int mi = 0; mi < 4; ++mi) {
#pragma unroll
        for (int r = 0; r < 4; ++r) {
            float* op = outb + (size_t)(rbase + mi * 16 + r) * NT + n0 + wn + fr;
#pragma unroll
            for (int ni = 0; ni < 4; ++ni)
                op[ni * 16] = acc[mi][ni][r] + bv[ni];
        }
    }
}

extern "C" void kernel_launch(void* const* d_in, const int* in_sizes, int n_in,
                              void* d_out, int out_size, void* d_ws, size_t ws_size,
                              hipStream_t stream) {
    const float* x    = (const float*)d_in[0];  // [NB][NS][ND] fp32
    const int*   hidx = (const int*)d_in[1];    // [NB] int32
    const float* W    = (const float*)d_in[2];  // [NH][ND][NT] fp32
    const float* bias = (const float*)d_in[3];  // [NH][NT] fp32
    float* out = (float*)d_out;

    unsigned short* xb = (unsigned short*)d_ws;            // 48 MiB bf16 x
    unsigned short* wt = xb + (size_t)NB * NS * ND;        // 48 MiB bf16 W^T

    // Fused convert: 24576 x-blocks + 6144 W-blocks
    cvt_kernel<<<dim3(XBLK + 32 * 24 * NH), dim3(256), 0, stream>>>(
        x, W, hidx, xb, wt);
    // GEMM: 1D swizzled grid covering (m,n,batch)
    gemm_kernel<<<dim3(2048), dim3(256), 0, stream>>>(xb, wt, bias, hidx, out);
}

// Round 4
// 322.611 us; speedup vs baseline: 1.2575x; 1.0940x over previous
//
#include <hip/hip_runtime.h>
#include <hip/hip_bf16.h>
#include <stdint.h>

// Problem constants (fixed by the reference file)
#define NB 8     // batch
#define NS 2048  // sequence
#define ND 1536  // model dim (K)
#define NT 2048  // padded tracks (N)
#define NH 8     // heads
#define NK2 (ND / 64)  // 24 K-iterations at BK=64

// NUM_TRACKS = [128,256,512,1024,2048,64,32,1024] -> ceil(nt/128) (in 128-tiles)
__constant__ int c_tiles[NH] = {1, 2, 4, 8, 16, 1, 1, 8};

typedef short bf16x8 __attribute__((ext_vector_type(8)));  // 8 bf16 (4 VGPRs)
typedef unsigned short u16x8 __attribute__((ext_vector_type(8)));
typedef float f32x4 __attribute__((ext_vector_type(4)));

__device__ __forceinline__ unsigned short f2bf(float f) {
    union { float f; unsigned u; } a; a.f = f;
    unsigned r = a.u + 0x7fffu + ((a.u >> 16) & 1u);  // RNE
    return (unsigned short)(r >> 16);
}

// ---------------- Fused prepass: x fp32->bf16  +  W transpose+convert -------
#define XBLK 24576
__global__ void cvt_kernel(const float* __restrict__ x,
                           const float* __restrict__ W,
                           const int* __restrict__ hidx,
                           unsigned short* __restrict__ xb,
                           unsigned short* __restrict__ Wt) {
    const int bid = blockIdx.x;
    const int tid = threadIdx.x;
    if (bid < XBLK) {
        const size_t i = (size_t)bid * 256 + tid;  // float4 index
        float4 v = ((const float4*)x)[i];
        ushort4 o;
        o.x = f2bf(v.x); o.y = f2bf(v.y); o.z = f2bf(v.z); o.w = f2bf(v.w);
        ((ushort4*)xb)[i] = o;
        return;
    }
    // W transpose: wid -> (t-tile 32, d-tile 24, h 8)
    const int wid = bid - XBLK;
    const int h = wid / (32 * 24);
    const int rem = wid % (32 * 24);
    const int t0 = (rem % 32) * 64;
    const int d0 = (rem / 32) * 64;
    bool used = false;
    for (int i = 0; i < NB; ++i) used |= (hidx[i] == h);
    if (!used || t0 >= c_tiles[h] * 128) return;

    __shared__ float tile[64][69];  // [d][t], padded
#pragma unroll
    for (int i = 0; i < 4; ++i) {
        const int idx = tid + i * 256;  // 1024 float4 chunks
        const int d = idx >> 4, c = (idx & 15) * 4;
        float4 v = *(const float4*)&W[((size_t)h * ND + d0 + d) * NT + t0 + c];
        tile[d][c] = v.x; tile[d][c + 1] = v.y;
        tile[d][c + 2] = v.z; tile[d][c + 3] = v.w;
    }
    __syncthreads();
    const int t = tid >> 2, dc = (tid & 3) * 16;  // 16 bf16 = 32 B per thread
    u16x8 o0, o1;
#pragma unroll
    for (int j = 0; j < 8; ++j) o0[j] = f2bf(tile[dc + j][t]);
#pragma unroll
    for (int j = 0; j < 8; ++j) o1[j] = f2bf(tile[dc + 8 + j][t]);
    unsigned short* p = Wt + ((size_t)h * NT + t0 + t) * ND + d0 + dc;
    *(u16x8*)p = o0;
    *(u16x8*)(p + 8) = o1;
}

// ---------------- GEMM: out[b] = x[b] @ W[h(b)] + bias[h(b)] ----------------
// 256x128 tile (8 waves), BK=64, XOR-swizzled LDS, deterministic balance:
// blocks [0, 8P) are compute (P = sum of valid 128-col tiles over batches),
// blocks [8P, 1024) are zero tiles. Grid is always 1024 = 8*(P + Pz).
#define GLDS(g, l)                                                      \
    __builtin_amdgcn_global_load_lds(                                   \
        (const __attribute__((address_space(1))) void*)(g),             \
        (__attribute__((address_space(3))) void*)(l), 16, 0, 0)

__global__ __launch_bounds__(512) void gemm_kernel(
    const unsigned short* __restrict__ xb,   // bf16 [NB][NS][ND]
    const unsigned short* __restrict__ wt,   // bf16 [NH][NT][ND]
    const float* __restrict__ bias,          // fp32 [NH][NT]
    const int* __restrict__ hidx,            // [NB]
    float* __restrict__ out)                 // fp32 [NB][NS][NT]
{
    const int tid = threadIdx.x;
    const int id = blockIdx.x;

    int hh[NB], tl[NB];
    int P = 0;
#pragma unroll
    for (int b = 0; b < NB; ++b) {
        hh[b] = hidx[b];
        tl[b] = c_tiles[hh[b]];
        P += tl[b];
    }
    const int C = 8 * P;

    int batch, m0, n0;
    if (id >= C) {
        // ---- zero tile: 256x128 of exact zeros ----
        const int Pz = 128 - P;
        const int z = id - C;
        int p = z % Pz;
        const int m = z / Pz;
        int b = 0;
        while (p >= 16 - tl[b]) { p -= 16 - tl[b]; ++b; }
        batch = b; n0 = (tl[b] + p) * 128; m0 = m * 256;
        float* outb = out + (size_t)batch * NS * NT;
        const int row = tid >> 1;
        const int c0 = (tid & 1) * 64;
        float4 zv = make_float4(0.f, 0.f, 0.f, 0.f);
        float4* ptr = (float4*)(outb + (size_t)(m0 + row) * NT + (n0 + c0));
#pragma unroll
        for (int j = 0; j < 16; ++j) ptr[j] = zv;
        return;
    }
    {
        int p = id % P;
        const int m = id / P;
        int b = 0;
        while (p >= tl[b]) { p -= tl[b]; ++b; }
        batch = b; n0 = p * 128; m0 = m * 256;
    }
    const int h = hh[batch];
    float* outb = out + (size_t)batch * NS * NT;

    __shared__ unsigned short As[256 * 64];  // [m][k], k-chunks XOR-swizzled
    __shared__ unsigned short Bs[128 * 64];  // [n][k] (B^T), swizzled

    const int lane = tid & 63;
    const int wave = tid >> 6;
    const int wm = (wave >> 1) * 64;   // 4 m-waves over 256 rows
    const int wn = (wave & 1) * 64;    // 2 n-waves over 128 cols
    const int fr = lane & 15;
    const int q = lane >> 4;           // k-group 0..3

    // Staging: A = 2048 16B chunks (4/thread), B = 1024 (2/thread).
    // LDS slot c=(row,sc) holds global k-chunk gc = sc ^ (row&7)  [bank swizzle]
    const unsigned short* ga[4];
    unsigned short* la[4];
#pragma unroll
    for (int j = 0; j < 4; ++j) {
        const int c = tid + 512 * j;
        const int r = c >> 3, gc = (c & 7) ^ (r & 7);
        ga[j] = xb + ((size_t)batch * NS + m0 + r) * ND + gc * 8;
        la[j] = As + c * 8;
    }
    const unsigned short* gb[2];
    unsigned short* lb[2];
#pragma unroll
    for (int j = 0; j < 2; ++j) {
        const int c = tid + 512 * j;
        const int r = c >> 3, gc = (c & 7) ^ (r & 7);
        gb[j] = wt + ((size_t)h * NT + n0 + r) * ND + gc * 8;
        lb[j] = Bs + c * 8;
    }

    // Reader-side swizzled k-offsets (shorts) for kk=0 / kk=1 sub-tiles.
    const int sw0 = ((q) ^ (fr & 7)) * 8;
    const int sw1 = ((q + 4) ^ (fr & 7)) * 8;

    f32x4 acc[4][4] = {};

    for (int it = 0; it < NK2; ++it) {
#pragma unroll
        for (int j = 0; j < 4; ++j) GLDS(ga[j], la[j]);
#pragma unroll
        for (int j = 0; j < 2; ++j) GLDS(gb[j], lb[j]);
        __syncthreads();
#pragma unroll
        for (int kk = 0; kk < 2; ++kk) {
            const int sw = kk ? sw1 : sw0;
            bf16x8 af[4], bfr[4];
#pragma unroll
            for (int mi = 0; mi < 4; ++mi)
                af[mi] = *(const bf16x8*)(As + (wm + mi * 16 + fr) * 64 + sw);
#pragma unroll
            for (int ni = 0; ni < 4; ++ni)
                bfr[ni] = *(const bf16x8*)(Bs + (wn + ni * 16 + fr) * 64 + sw);
#pragma unroll
            for (int mi = 0; mi < 4; ++mi)
#pragma unroll
                for (int ni = 0; ni < 4; ++ni)
                    acc[mi][ni] = __builtin_amdgcn_mfma_f32_16x16x32_bf16(
                        af[mi], bfr[ni], acc[mi][ni], 0, 0, 0);
        }
        __syncthreads();
#pragma unroll
        for (int j = 0; j < 4; ++j) ga[j] += 64;
#pragma unroll
        for (int j = 0; j < 2; ++j) gb[j] += 64;
    }

    // Epilogue: C/D layout col=lane&15, row=(lane>>4)*4+reg
    float bv[4];
#pragma unroll
    for (int ni = 0; ni < 4; ++ni)
        bv[ni] = bias[(size_t)h * NT + n0 + wn + ni * 16 + fr];

    const int rbase = m0 + wm + q * 4;
#pragma unroll
    for (int mi = 0; mi < 4; ++mi) {
#pragma unroll
        for (int r = 0; r < 4; ++r) {
            float* op = outb + (size_t)(rbase + mi * 16 + r) * NT + n0 + wn + fr;
#pragma unroll
            for (int ni = 0; ni < 4; ++ni)
                op[ni * 16] = acc[mi][ni][r] + bv[ni];
        }
    }
}

extern "C" void kernel_launch(void* const* d_in, const int* in_sizes, int n_in,
                              void* d_out, int out_size, void* d_ws, size_t ws_size,
                              hipStream_t stream) {
    const float* x    = (const float*)d_in[0];  // [NB][NS][ND] fp32
    const int*   hidx = (const int*)d_in[1];    // [NB] int32
    const float* W    = (const float*)d_in[2];  // [NH][ND][NT] fp32
    const float* bias = (const float*)d_in[3];  // [NH][NT] fp32
    float* out = (float*)d_out;

    unsigned short* xb = (unsigned short*)d_ws;            // 48 MiB bf16 x
    unsigned short* wt = xb + (size_t)NB * NS * ND;        // 48 MiB bf16 W^T

    // Fused convert: 24576 x-blocks + 6144 W-blocks
    cvt_kernel<<<dim3(XBLK + 32 * 24 * NH), dim3(256), 0, stream>>>(
        x, W, hidx, xb, wt);
    // GEMM: 1024 blocks = 8 m-tiles x 16 n-tiles x 8 batches, balanced decode
    gemm_kernel<<<dim3(1024), dim3(512), 0, stream>>>(xb, wt, bias, hidx, out);
}